// Round 5
// baseline (170.716 us; speedup 1.0000x reference)
//
#include <hip/hip_runtime.h>
#include <math.h>

#define NCL  27
#define CCH  512
#define HWPX 9216            // 96*96
#define NB   16
#define NPIX (NB * HWPX)     // 147456
#define EPSN 1e-12f
#define PXT  64              // pixels per block (1 wave per block)
#define CHK  16              // channels per staged chunk
#define NCHK (CCH / CHK)     // 32 chunks

typedef float v2f __attribute__((ext_vector_type(2)));

// fire-and-forget global->LDS DMA: per-lane global src, LDS dest = uniform
// base + lane*16 (linear)
__device__ __forceinline__ void gload_lds16(const float* g, float* lds) {
    __builtin_amdgcn_global_load_lds(
        (const __attribute__((address_space(1))) unsigned int*)g,
        (__attribute__((address_space(3))) unsigned int*)lds,
        16, 0, 0);
}

// ---------------------------------------------------------------------------
// k0: normalize clusters and transpose into chunk-major layout
//   clT[t][n][c] = cl[n][t*16+c] * inv_norm(cl[n])   (t=0..31, n padded to 32)
// so k1 can stage one contiguous 2KB slice per chunk. Also zero loss_acc.
// ---------------------------------------------------------------------------
__global__ __launch_bounds__(64) void k0_prep(const float* __restrict__ cl,
                                              float* __restrict__ clT,
                                              float* __restrict__ loss_acc) {
    const int n = blockIdx.x;
    const int t = threadIdx.x;
    const float* row = cl + n * CCH;
    float ss = 0.f;
#pragma unroll
    for (int i = 0; i < CCH / 64; ++i) {
        float v = row[i * 64 + t];
        ss = fmaf(v, v, ss);
    }
#pragma unroll
    for (int off = 32; off > 0; off >>= 1)
        ss += __shfl_xor(ss, off, 64);                // all lanes get sum
    const float inv = 1.0f / fmaxf(sqrtf(ss), EPSN);
#pragma unroll
    for (int j = 0; j < 8; ++j) {
        const int cg = 8 * t + j;                     // 0..511
        const int tt = cg >> 4;
        const int c  = cg & 15;
        clT[tt * 512 + n * 16 + c] = row[cg] * inv;   // [32][32][16] layout
    }
    if (n == 0 && t == 0) loss_acc[0] = 0.f;
}

// ---------------------------------------------------------------------------
// k1: fused main kernel. 1 wave per block, 64 pixels, lane owns one pixel.
//  - x chunk (16ch x 64px, 4KB) AND cluster chunk (2KB) double-buffered in
//    LDS via global_load_lds; stage(t+1) issued before compute(t).
//  - cluster operands read as broadcast ds_read_b128 (NOT s_load: 55KB
//    thrashes the scalar cache and serializes on scalar-miss latency).
//  - 2304 blocks -> 9 independent pipeline groups per CU.
// ---------------------------------------------------------------------------
__global__ __launch_bounds__(64) void k1_main(const float* __restrict__ x,
                                              const float* __restrict__ clT,
                                              const float* __restrict__ alpha_p,
                                              float* __restrict__ out,
                                              float* __restrict__ loss_acc) {
    __shared__ float xt[2][CHK][PXT];                 // 2 x 4KB
    __shared__ float ct[2][32][16];                   // 2 x 2KB

    const int l   = threadIdx.x;                      // lane = pixel
    const int p0  = blockIdx.x * PXT;
    const int b   = p0 / HWPX;                        // uniform (64 | 9216)
    const int hw0 = p0 - b * HWPX;
    const float* xg = x + (size_t)b * CCH * HWPX + hw0;

    v2f acc2[NCL];
#pragma unroll
    for (int n = 0; n < NCL; ++n) acc2[n] = (v2f){0.f, 0.f};
    v2f ss2 = (v2f){0.f, 0.f};

    // ---- staging helpers (all lane-linear LDS dests) ----
    // x: one glds covers 4 rows of 64px: lane src = row (l>>4), 16B col (l&15)
#define STAGE(tc, bf)                                                        \
    {                                                                        \
        const float* gc = xg + (size_t)(tc) * CHK * HWPX;                    \
        _Pragma("unroll")                                                    \
        for (int q = 0; q < 4; ++q)                                          \
            gload_lds16(gc + (size_t)(4 * q + (l >> 4)) * HWPX + (l & 15) * 4,\
                        &xt[bf][4 * q][0]);                                  \
        const float* gcl = clT + (tc) * 512;                                 \
        gload_lds16(gcl + l * 4,       &ct[bf][0][0]);                       \
        gload_lds16(gcl + 256 + l * 4, &ct[bf][16][0]);                      \
    }

    STAGE(0, 0);
    __syncthreads();

    int buf = 0;
    for (int t = 0; t < NCHK; ++t) {
        if (t + 1 < NCHK) STAGE(t + 1, buf ^ 1);      // in flight during compute

        // ---- compute chunk t ----
        float xv[CHK];
#pragma unroll
        for (int i = 0; i < CHK; ++i)
            xv[i] = xt[buf][i][l];                    // ds_read_b32, 2-way free
        v2f xp[CHK / 2];
#pragma unroll
        for (int i = 0; i < CHK / 2; ++i)
            xp[i] = (v2f){xv[2 * i], xv[2 * i + 1]};
#pragma unroll
        for (int i = 0; i < CHK / 2; ++i)
            ss2 = __builtin_elementwise_fma(xp[i], xp[i], ss2);
#pragma unroll
        for (int n = 0; n < NCL; ++n) {
            v2f a = acc2[n];
#pragma unroll
            for (int i = 0; i < 4; ++i) {
                float4 cp = *(const float4*)&ct[buf][n][4 * i];  // broadcast b128
                a = __builtin_elementwise_fma(xp[2 * i],     (v2f){cp.x, cp.y}, a);
                a = __builtin_elementwise_fma(xp[2 * i + 1], (v2f){cp.z, cp.w}, a);
            }
            acc2[n] = a;
        }

        __syncthreads();                              // drains stage(t+1)
        buf ^= 1;
    }
#undef STAGE

    // ---- epilogue: per-lane softmax (cluster norms already folded in) ----
    const float ssum  = ss2.x + ss2.y;
    const float inv_x = 1.0f / fmaxf(sqrtf(ssum), EPSN);
    const float alpha = alpha_p[0];

    float ip[NCL], ex[NCL];
    float m = -1e30f;
#pragma unroll
    for (int n = 0; n < NCL; ++n) {
        ip[n] = (acc2[n].x + acc2[n].y) * inv_x;      // cosine similarity
        float s = ip[n] * alpha;
        ex[n] = s;
        m = fmaxf(m, s);
    }
    float sum = 0.f;
#pragma unroll
    for (int n = 0; n < NCL; ++n) {
        float e = __expf(ex[n] - m);
        ex[n] = e;
        sum += e;
    }
    const float inv_sum = 1.0f / sum;

    float lterm = 0.f;
    float* ob = out + 1 + (size_t)b * (NCL * HWPX) + hw0 + l;
#pragma unroll
    for (int n = 0; n < NCL; ++n) {
        float pr = ex[n] * inv_sum;
        ob[(size_t)n * HWPX] = pr;                    // coalesced 256B/wave
        lterm = fmaf(pr, ip[n], lterm);
    }

#pragma unroll
    for (int off = 32; off > 0; off >>= 1)
        lterm += __shfl_down(lterm, off, 64);
    if (l == 0)
        atomicAdd(loss_acc, lterm);
}

// ---------------------------------------------------------------------------
// k2: finalize loss
// ---------------------------------------------------------------------------
__global__ void k2_fin(const float* __restrict__ loss_acc,
                       float* __restrict__ out) {
    out[0] = -loss_acc[0] * (1.0f / (float)NPIX);
}

extern "C" void kernel_launch(void* const* d_in, const int* in_sizes, int n_in,
                              void* d_out, int out_size, void* d_ws, size_t ws_size,
                              hipStream_t stream) {
    const float* x     = (const float*)d_in[0];
    const float* cl    = (const float*)d_in[1];
    const float* alpha = (const float*)d_in[2];
    float* out = (float*)d_out;
    float* ws  = (float*)d_ws;

    float* loss_acc = ws;            // 1 float
    float* clT      = ws + 256;      // 32*32*16 = 16384 floats (64KB), 1KB-aligned

    hipLaunchKernelGGL(k0_prep, dim3(NCL), dim3(64), 0, stream, cl, clT, loss_acc);
    hipLaunchKernelGGL(k1_main, dim3(NPIX / PXT), dim3(64), 0, stream,
                       x, clT, alpha, out, loss_acc);
    hipLaunchKernelGGL(k2_fin, dim3(1), dim3(1), 0, stream, loss_acc, out);
}

// Round 7
// 106.113 us; speedup vs baseline: 1.6088x; 1.6088x over previous
//
#include <hip/hip_runtime.h>
#include <math.h>

#define NCL  27
#define CCH  512
#define HWPX 9216            // 96*96
#define NB   16
#define NPIX (NB * HWPX)     // 147456
#define EPSN 1e-12f
#define NCHK 32              // K chunks of 16

typedef short  short8  __attribute__((ext_vector_type(8)));
typedef float  f32x16  __attribute__((ext_vector_type(16)));

// manual bf16 RNE conversion (bit math)
__device__ __forceinline__ unsigned short f2bf(float f) {
    unsigned u = __float_as_uint(f);
    return (unsigned short)((u + 0x7fffu + ((u >> 16) & 1u)) >> 16);
}
__device__ __forceinline__ float bf2f(unsigned short h) {
    return __uint_as_float(((unsigned)h) << 16);
}

// ---------------------------------------------------------------------------
// k0: normalize clusters (fp32), split into bf16 hi/lo, write A-fragments in
// the 32x32x16 MFMA lane layout:
//   A[row=m][k] -> clA[chunk][lane][j], lane = m + 32*half, k = chunk*16+8*half+j
// rows 27..31 zero-pad. grid = 32 x 64.
// ---------------------------------------------------------------------------
__global__ __launch_bounds__(64) void k0_prep(const float* __restrict__ cl,
                                              unsigned short* __restrict__ clAhi,
                                              unsigned short* __restrict__ clAlo,
                                              float* __restrict__ loss_acc) {
    const int n = blockIdx.x;            // A row 0..31
    const int t = threadIdx.x;
    float inv = 0.f;
    if (n < NCL) {
        const float* row = cl + n * CCH;
        float ss = 0.f;
#pragma unroll
        for (int i = 0; i < CCH / 64; ++i) {
            float v = row[i * 64 + t];
            ss = fmaf(v, v, ss);
        }
#pragma unroll
        for (int off = 32; off > 0; off >>= 1)
            ss += __shfl_xor(ss, off, 64);
        inv = 1.0f / fmaxf(sqrtf(ss), EPSN);
    }
    const int chunk = t >> 1;
    const int half  = t & 1;
    const int lane  = n + 32 * half;
    const size_t base = ((size_t)chunk * 64 + lane) * 8;
#pragma unroll
    for (int j = 0; j < 8; ++j) {
        const int k = chunk * 16 + 8 * half + j;
        float v = (n < NCL) ? cl[n * CCH + k] * inv : 0.f;
        unsigned short h = f2bf(v);
        float lo = v - bf2f(h);
        clAhi[base + j] = h;
        clAlo[base + j] = f2bf(lo);
    }
    if (n == 0 && t == 0) loss_acc[0] = 0.f;
}

// ---------------------------------------------------------------------------
// k1: streaming MFMA kernel. NO LDS, NO barriers.
//  Wave = one 32-pixel tile x all 512 channels. Per K=16 chunk: 8 coalesced
//  x loads/lane (fp32, read-once), 2 dwordx4 A-fragment loads (L2-resident),
//  in-reg bf16 hi/lo split, 3 MFMAs (hi*hi + lo*hi + hi*lo ~= fp32).
//  C: col=lane&31=pixel, row=(r&3)+8*(r>>2)+4*half=cluster.
//  VALID rows are 0..26: half0 covers {0-3,8-11,16-19,24-26}(r<15!),
//  half1 covers {4-7,12-15,20-23}; r==15/half0 -> row 27 = PAD (round-6 bug).
// ---------------------------------------------------------------------------
__global__ __launch_bounds__(256) void k1_main(const float* __restrict__ x,
                                               const unsigned short* __restrict__ clAhi,
                                               const unsigned short* __restrict__ clAlo,
                                               const float* __restrict__ alpha_p,
                                               float* __restrict__ out,
                                               float* __restrict__ loss_acc) {
    const int tid  = threadIdx.x;
    const int l    = tid & 63;
    const int wv   = tid >> 6;
    const int tile = blockIdx.x * 4 + wv;
    const int px0  = tile * 32;
    const int b    = px0 / HWPX;                  // uniform per wave (32|9216)
    const int hw0  = px0 - b * HWPX;
    const int col  = l & 31;                      // pixel within tile
    const int half = l >> 5;                      // k-half

    const float* xg = x + ((size_t)b * CCH + 8 * half) * HWPX + hw0 + col;
    const unsigned short* pAh = clAhi + (size_t)l * 8;
    const unsigned short* pAl = clAlo + (size_t)l * 8;

    f32x16 acc = {0.f, 0.f, 0.f, 0.f, 0.f, 0.f, 0.f, 0.f,
                  0.f, 0.f, 0.f, 0.f, 0.f, 0.f, 0.f, 0.f};
    float ss = 0.f;

#pragma unroll 2
    for (int t = 0; t < NCHK; ++t) {
        float xv[8];
#pragma unroll
        for (int j = 0; j < 8; ++j)
            xv[j] = xg[(size_t)(t * 16 + j) * HWPX];   // coalesced 128B/half-wave

        short8 ah = *(const short8*)(pAh + (size_t)t * 512);   // dwordx4, L2-hit
        short8 al = *(const short8*)(pAl + (size_t)t * 512);

        short8 bh, bl;
#pragma unroll
        for (int j = 0; j < 8; ++j) {
            ss = fmaf(xv[j], xv[j], ss);               // exact fp32 self-norm
            unsigned short h = f2bf(xv[j]);
            bh[j] = (short)h;
            bl[j] = (short)f2bf(xv[j] - bf2f(h));
        }

        acc = __builtin_amdgcn_mfma_f32_32x32x16_bf16(ah, bh, acc, 0, 0, 0);
        acc = __builtin_amdgcn_mfma_f32_32x32x16_bf16(al, bh, acc, 0, 0, 0);
        acc = __builtin_amdgcn_mfma_f32_32x32x16_bf16(ah, bl, acc, 0, 0, 0);
    }

    // ---- epilogue ----
    ss += __shfl_xor(ss, 32, 64);                 // combine k-halves of pixel
    const float inv_x = 1.0f / fmaxf(sqrtf(ss), EPSN);
    const float alpha = alpha_p[0];

    float ip[16], ex[16];
#pragma unroll
    for (int r = 0; r < 16; ++r) {
        ip[r] = acc[r] * inv_x;                   // cosine (cl-norm folded in A)
        ex[r] = ip[r] * alpha;
    }

    // valid (row<27) predicate: r<12 always; r in 12..14 only on half 0
    float m = -1e30f;
#pragma unroll
    for (int r = 0; r < 12; ++r) m = fmaxf(m, ex[r]);
    if (half == 0) {
#pragma unroll
        for (int r = 12; r < 15; ++r) m = fmaxf(m, ex[r]);
    }
    m = fmaxf(m, __shfl_xor(m, 32, 64));          // max over all 27

    float sum = 0.f;
#pragma unroll
    for (int r = 0; r < 12; ++r) {
        ex[r] = __expf(ex[r] - m);
        sum += ex[r];
    }
#pragma unroll
    for (int r = 12; r < 16; ++r) {
        float e = (half == 0 && r < 15) ? __expf(ex[r] - m) : 0.f;
        ex[r] = e;
        sum += e;
    }
    sum += __shfl_xor(sum, 32, 64);               // denom over all 27
    const float inv_sum = 1.0f / sum;

    float lterm = 0.f;
    float* ob = out + 1 + (size_t)b * (NCL * HWPX) + hw0 + col;
#pragma unroll
    for (int r = 0; r < 16; ++r) {
        const int row = (r & 3) + 8 * (r >> 2) + 4 * half;
        if (r < 12 || (half == 0 && r < 15)) {    // row < 27 only
            float pr = ex[r] * inv_sum;
            ob[(size_t)row * HWPX] = pr;          // coalesced 128B segments
            lterm = fmaf(pr, ip[r], lterm);
        }
    }

    // per-(pixel,half) partials; all 64 lanes sum -> each (pixel,row) once
#pragma unroll
    for (int off = 32; off > 0; off >>= 1)
        lterm += __shfl_xor(lterm, off, 64);
    if (l == 0)
        atomicAdd(loss_acc, lterm);
}

// ---------------------------------------------------------------------------
// k2: finalize loss
// ---------------------------------------------------------------------------
__global__ void k2_fin(const float* __restrict__ loss_acc,
                       float* __restrict__ out) {
    out[0] = -loss_acc[0] * (1.0f / (float)NPIX);
}

extern "C" void kernel_launch(void* const* d_in, const int* in_sizes, int n_in,
                              void* d_out, int out_size, void* d_ws, size_t ws_size,
                              hipStream_t stream) {
    const float* x     = (const float*)d_in[0];
    const float* cl    = (const float*)d_in[1];
    const float* alpha = (const float*)d_in[2];
    float* out = (float*)d_out;

    float*          loss_acc = (float*)d_ws;
    unsigned short* clAhi    = (unsigned short*)((char*)d_ws + 1024);
    unsigned short* clAlo    = clAhi + 32 * 64 * 8;      // +32KB

    hipLaunchKernelGGL(k0_prep, dim3(32), dim3(64), 0, stream,
                       cl, clAhi, clAlo, loss_acc);
    hipLaunchKernelGGL(k1_main, dim3(NPIX / 128), dim3(256), 0, stream,
                       x, clAhi, clAlo, alpha, out, loss_acc);
    hipLaunchKernelGGL(k2_fin, dim3(1), dim3(1), 0, stream, loss_acc, out);
}

// Round 8
// 82.811 us; speedup vs baseline: 2.0615x; 1.2814x over previous
//
#include <hip/hip_runtime.h>
#include <math.h>

#define NCL  27
#define CCH  512
#define HWPX 9216            // 96*96
#define NB   16
#define NPIX (NB * HWPX)     // 147456
#define EPSN 1e-12f
#define NCHK 32              // K chunks of 16

typedef short        short8 __attribute__((ext_vector_type(8)));
typedef unsigned int uint4v __attribute__((ext_vector_type(4)));
typedef float        f32x16 __attribute__((ext_vector_type(16)));

// RNE bf16 conversion for the (one-time) cluster prep
__device__ __forceinline__ unsigned short f2bf(float f) {
    unsigned u = __float_as_uint(f);
    return (unsigned short)((u + 0x7fffu + ((u >> 16) & 1u)) >> 16);
}
__device__ __forceinline__ float bf2f(unsigned short h) {
    return __uint_as_float(((unsigned)h) << 16);
}

// ---------------------------------------------------------------------------
// k0: normalize clusters (fp32), split into bf16 hi/lo (RNE), write
// A-fragments in 32x32x16 MFMA lane layout:
//   A[row=m][k] -> clA[chunk][lane][j], lane = m + 32*half, k = chunk*16+8*half+j
// rows 27..31 zero-pad. Also zero the 32 loss slots. grid = 32 x 64.
// ---------------------------------------------------------------------------
__global__ __launch_bounds__(64) void k0_prep(const float* __restrict__ cl,
                                              unsigned short* __restrict__ clAhi,
                                              unsigned short* __restrict__ clAlo,
                                              float* __restrict__ loss_acc) {
    const int n = blockIdx.x;            // A row 0..31
    const int t = threadIdx.x;
    float inv = 0.f;
    if (n < NCL) {
        const float* row = cl + n * CCH;
        float ss = 0.f;
#pragma unroll
        for (int i = 0; i < CCH / 64; ++i) {
            float v = row[i * 64 + t];
            ss = fmaf(v, v, ss);
        }
#pragma unroll
        for (int off = 32; off > 0; off >>= 1)
            ss += __shfl_xor(ss, off, 64);
        inv = 1.0f / fmaxf(sqrtf(ss), EPSN);
    }
    const int chunk = t >> 1;
    const int half  = t & 1;
    const int lane  = n + 32 * half;
    const size_t base = ((size_t)chunk * 64 + lane) * 8;
#pragma unroll
    for (int j = 0; j < 8; ++j) {
        const int k = chunk * 16 + 8 * half + j;
        float v = (n < NCL) ? cl[n * CCH + k] * inv : 0.f;
        unsigned short h = f2bf(v);
        float lo = v - bf2f(h);
        clAhi[base + j] = h;
        clAlo[base + j] = f2bf(lo);
    }
    if (n == 0 && t < 32) loss_acc[t * 32] = 0.f;   // 32 line-padded slots
}

// ---------------------------------------------------------------------------
// k1: streaming MFMA kernel. NO LDS, NO barriers, 1-wave blocks (grid 4608).
//  Wave = 32-pixel tile x 512 channels. Per K=16 chunk: 8 coalesced x loads
//  (fp32, read-once), 2 dwordx4 A-fragment loads (L2-resident), cheap
//  TRUNCATION hi/lo split (hi = top16 bits, lo = v - hi exact, bl = trunc16),
//  3 MFMAs (ah*bh + al*bh + ah*bl ~= fp32 product, err ~2^-16 rel).
//  C: col=lane&31=pixel, row=(r&3)+8*(r>>2)+4*half; valid rows < 27 only
//  (r<12 always, r=12..14 on half 0; r==15/half0 is pad row 27).
// ---------------------------------------------------------------------------
__global__ __launch_bounds__(64) void k1_main(const float* __restrict__ x,
                                              const unsigned short* __restrict__ clAhi,
                                              const unsigned short* __restrict__ clAlo,
                                              const float* __restrict__ alpha_p,
                                              float* __restrict__ out,
                                              float* __restrict__ loss_acc) {
    const int l    = threadIdx.x;
    const int px0  = blockIdx.x * 32;
    const int b    = px0 / HWPX;                  // uniform (32 | 9216)
    const int hw0  = px0 - b * HWPX;
    const int col  = l & 31;                      // pixel within tile
    const int half = l >> 5;                      // k-half

    const float* xg = x + ((size_t)b * CCH + 8 * half) * HWPX + hw0 + col;
    const unsigned short* pAh = clAhi + (size_t)l * 8;
    const unsigned short* pAl = clAlo + (size_t)l * 8;

    f32x16 acc = {0.f, 0.f, 0.f, 0.f, 0.f, 0.f, 0.f, 0.f,
                  0.f, 0.f, 0.f, 0.f, 0.f, 0.f, 0.f, 0.f};
    float ss = 0.f;

#pragma unroll 2
    for (int t = 0; t < NCHK; ++t) {
        float xv[8];
#pragma unroll
        for (int j = 0; j < 8; ++j)
            xv[j] = xg[(size_t)(t * 16 + j) * HWPX];   // coalesced 128B/half-wave

        short8 ah = *(const short8*)(pAh + (size_t)t * 512);   // dwordx4, L2-hit
        short8 al = *(const short8*)(pAl + (size_t)t * 512);

        unsigned hb[8], ub[8], lb[8];
#pragma unroll
        for (int j = 0; j < 8; ++j) {
            ss = fmaf(xv[j], xv[j], ss);               // exact fp32 self-norm
            ub[j] = __float_as_uint(xv[j]);
            hb[j] = ub[j] & 0xFFFF0000u;               // truncated bf16 (as f32 bits)
            lb[j] = __float_as_uint(xv[j] - __uint_as_float(hb[j]));  // exact lo
        }
        uint4v bhp, blp;
#pragma unroll
        for (int i = 0; i < 4; ++i) {
            bhp[i] = (ub[2 * i] >> 16) | hb[2 * i + 1];
            blp[i] = (lb[2 * i] >> 16) | (lb[2 * i + 1] & 0xFFFF0000u);
        }
        short8 bh = __builtin_bit_cast(short8, bhp);
        short8 bl = __builtin_bit_cast(short8, blp);

        acc = __builtin_amdgcn_mfma_f32_32x32x16_bf16(ah, bh, acc, 0, 0, 0);
        acc = __builtin_amdgcn_mfma_f32_32x32x16_bf16(al, bh, acc, 0, 0, 0);
        acc = __builtin_amdgcn_mfma_f32_32x32x16_bf16(ah, bl, acc, 0, 0, 0);
    }

    // ---- epilogue ----
    ss += __shfl_xor(ss, 32, 64);                 // combine k-halves of pixel
    const float inv_x = 1.0f / fmaxf(sqrtf(ss), EPSN);
    const float alpha = alpha_p[0];

    float ip[16], ex[16];
#pragma unroll
    for (int r = 0; r < 16; ++r) {
        ip[r] = acc[r] * inv_x;                   // cosine (cl-norm folded in A)
        ex[r] = ip[r] * alpha;
    }

    // valid (row<27): r<12 always; r in 12..14 only on half 0
    float m = -1e30f;
#pragma unroll
    for (int r = 0; r < 12; ++r) m = fmaxf(m, ex[r]);
    if (half == 0) {
#pragma unroll
        for (int r = 12; r < 15; ++r) m = fmaxf(m, ex[r]);
    }
    m = fmaxf(m, __shfl_xor(m, 32, 64));          // max over all 27

    float sum = 0.f;
#pragma unroll
    for (int r = 0; r < 12; ++r) {
        ex[r] = __expf(ex[r] - m);
        sum += ex[r];
    }
#pragma unroll
    for (int r = 12; r < 16; ++r) {
        float e = (half == 0 && r < 15) ? __expf(ex[r] - m) : 0.f;
        ex[r] = e;
        sum += e;
    }
    sum += __shfl_xor(sum, 32, 64);               // denom over all 27
    const float inv_sum = 1.0f / sum;

    float lterm = 0.f;
    float* ob = out + 1 + (size_t)b * (NCL * HWPX) + hw0 + col;
#pragma unroll
    for (int r = 0; r < 16; ++r) {
        const int row = (r & 3) + 8 * (r >> 2) + 4 * half;
        if (r < 12 || (half == 0 && r < 15)) {    // row < 27 only
            float pr = ex[r] * inv_sum;
            ob[(size_t)row * HWPX] = pr;          // coalesced 128B segments
            lterm = fmaf(pr, ip[r], lterm);
        }
    }

    // per-(pixel,half) partials; 64-lane sum counts each (pixel,row) once
#pragma unroll
    for (int off = 32; off > 0; off >>= 1)
        lterm += __shfl_xor(lterm, off, 64);
    if (l == 0)
        atomicAdd(&loss_acc[(blockIdx.x & 31) * 32], lterm);   // 32-way spread
}

// ---------------------------------------------------------------------------
// k2: finalize loss (sum the 32 slots)
// ---------------------------------------------------------------------------
__global__ void k2_fin(const float* __restrict__ loss_acc,
                       float* __restrict__ out) {
    float s = 0.f;
#pragma unroll
    for (int i = 0; i < 32; ++i) s += loss_acc[i * 32];
    out[0] = -s * (1.0f / (float)NPIX);
}

extern "C" void kernel_launch(void* const* d_in, const int* in_sizes, int n_in,
                              void* d_out, int out_size, void* d_ws, size_t ws_size,
                              hipStream_t stream) {
    const float* x     = (const float*)d_in[0];
    const float* cl    = (const float*)d_in[1];
    const float* alpha = (const float*)d_in[2];
    float* out = (float*)d_out;

    float*          loss_acc = (float*)d_ws;                       // 32 slots x 128B
    unsigned short* clAhi    = (unsigned short*)((char*)d_ws + 4096);
    unsigned short* clAlo    = clAhi + 32 * 64 * 8;                // +32KB

    hipLaunchKernelGGL(k0_prep, dim3(32), dim3(64), 0, stream,
                       cl, clAhi, clAlo, loss_acc);
    hipLaunchKernelGGL(k1_main, dim3(NPIX / 32), dim3(64), 0, stream,
                       x, clAhi, clAlo, alpha, out, loss_acc);
    hipLaunchKernelGGL(k2_fin, dim3(1), dim3(1), 0, stream, loss_acc, out);
}